// Round 7
// baseline (1382.199 us; speedup 1.0000x reference)
//
#include <hip/hip_runtime.h>
#include <hip/hip_cooperative_groups.h>
#include <math.h>

namespace cg = cooperative_groups;

#define NB 256
#define NR 1152

typedef unsigned short u16;
typedef __bf16 bf16x8 __attribute__((ext_vector_type(8)));
typedef float f32x4 __attribute__((ext_vector_type(4)));

__device__ __forceinline__ void load_lds16(const void* g, void* l) {
  __builtin_amdgcn_global_load_lds(
      (const __attribute__((address_space(1))) void*)g,
      (__attribute__((address_space(3))) void*)l, 16, 0, 0);
}

__device__ __forceinline__ u16 bf16_rn(float f) {
  unsigned u = __float_as_uint(f);
  unsigned r = (u + 0x7fffu + ((u >> 16) & 1u)) >> 16;
  return (u16)r;
}

// ================= k_setup: fused init + prep_w + conv1 =================
__global__ __launch_bounds__(256)
void k_setup(const float* __restrict__ x, float* __restrict__ out,
             float* __restrict__ praw2, float* __restrict__ bijz,
             const float* __restrict__ pw, u16* __restrict__ Bwh,
             u16* __restrict__ Bwl, const float* __restrict__ w1,
             const float* __restrict__ b1, u16* __restrict__ yh,
             u16* __restrict__ yl) {
  __shared__ __align__(16) float smem[6016];
  int bid = blockIdx.x, t = threadIdx.x;
  float4 z = {0.f, 0.f, 0.f, 0.f};
  if (bid < 196) {
    ((float4*)out)[bid * 256 + t] = ((const float4*)x)[bid * 256 + t];
  } else if (bid < 2500) {
    ((float4*)praw2)[(bid - 196) * 256 + t] = z;
  } else if (bid < 2552) {
    int i = (bid - 2500) * 256 + t;
    if (i < 13120) ((float4*)bijz)[i] = z;
  } else if (bid < 4600) {
    float* ld = smem;
    int q = bid - 2552;
    int icb = q & 7, oc = q >> 3;
    const float* src = pw + ((size_t)oc * 256 + icb * 32) * 81;
    for (int j = t; j < 2592; j += 256) ld[j] = src[j];
    __syncthreads();
    for (int j = t; j < 2592; j += 256) {
      int tap = j >> 5, icl = j & 31;
      float v = ld[icl * 81 + tap];
      u16 h = bf16_rn(v);
      float hf = __uint_as_float(((unsigned)h) << 16);
      u16 l = bf16_rn(v - hf);
      size_t o = ((size_t)(tap * 8 + icb) * 256 + oc) * 32 + icl;
      Bwh[o] = h;
      Bwl[o] = l;
    }
  } else {
    float* x_lds = smem;        // 896
    float* yt = smem + 896;     // 5120
    int q = bid - 4600;
    int icc = q & 1, b = q >> 1;
    for (int j = t; j < 784; j += 256)
      x_lds[(j / 28) * 32 + (j % 28)] = x[b * 784 + j];
    if (t < 112) x_lds[(t >> 2) * 32 + 28 + (t & 3)] = 0.f;
    int icl = t & 127, half = t >> 7;
    int ic = icc * 128 + icl;
    float bias = b1[ic];
    float wreg[81];
#pragma unroll
    for (int j = 0; j < 81; ++j) wreg[j] = w1[ic * 81 + j];
    __syncthreads();
    for (int r0 = 0; r0 < 10; ++r0) {
      int row = half * 10 + r0;
      float vout[20];
#pragma unroll
      for (int seg = 0; seg < 3; ++seg) {
        const int c0 = (seg == 0) ? 0 : (seg == 1 ? 8 : 16);
        const int W = (seg == 2) ? 4 : 8;
        float a[8];
#pragma unroll
        for (int i = 0; i < 8; ++i) a[i] = bias;
#pragma unroll
        for (int kh = 0; kh < 9; ++kh) {
          float xv[16];
          const float* xr = &x_lds[(row + kh) * 32 + c0];
          *(float4*)&xv[0] = *(const float4*)&xr[0];
          *(float4*)&xv[4] = *(const float4*)&xr[4];
          *(float4*)&xv[8] = *(const float4*)&xr[8];
          *(float4*)&xv[12] = *(const float4*)&xr[12];
#pragma unroll
          for (int kw = 0; kw < 9; ++kw) {
            float wv = wreg[kh * 9 + kw];
#pragma unroll
            for (int i = 0; i < W; ++i) a[i] = fmaf(xv[i + kw], wv, a[i]);
          }
        }
#pragma unroll
        for (int i = 0; i < W; ++i) vout[c0 + i] = fmaxf(a[i], 0.f);
      }
#pragma unroll
      for (int c = 0; c < 20; ++c) yt[half * 2560 + c * 128 + icl] = vout[c];
      __syncthreads();
#pragma unroll
      for (int j = 0; j < 20; ++j) {
        int idx = j * 2 + half;
        int hh = (idx >= 20) ? 1 : 0;
        int cc = idx - hh * 20;
        float v = yt[hh * 2560 + cc * 128 + icl];
        int rw = hh * 10 + r0;
        u16 h = bf16_rn(v);
        float hf = __uint_as_float(((unsigned)h) << 16);
        u16 l = bf16_rn(v - hf);
        size_t o = ((size_t)(rw * 20 + cc) * 256 + b) * 256 + icc * 128 + icl;
        yh[o] = h;
        yl[o] = l;
      }
      __syncthreads();
    }
  }
}

// ======= MFMA implicit GEMM (R4 measured-best: BK=32, 16 KB LDS) =======
// grid (36, 36 p): bx = mt(1b) nt(1b) ks(0..8). phase = ks/3, kh-seg = ks%3
__global__ __launch_bounds__(256)
void k_mfma(const u16* __restrict__ yh, const u16* __restrict__ yl,
            const u16* __restrict__ Bwh, const u16* __restrict__ Bwl,
            float* __restrict__ praw2) {
  __shared__ __align__(16) u16 As[4096];
  __shared__ __align__(16) u16 Bs[4096];
  int t = threadIdx.x;
  int lane = t & 63, w = t >> 6;
  int lanelo = lane & 15, quad = lane >> 4;
  int bx = blockIdx.x;
  int mt = bx & 1, nt = (bx >> 1) & 1, ks = bx >> 2;
  int phase = ks / 3, seg = ks - phase * 3;
  int m0 = mt * 128, n0 = nt * 128;
  int p = blockIdx.y;
  int ph = p / 6, pwc = p - ph * 6;
  int mw = (w & 1) * 64, nw = (w >> 1) * 64;
  const u16* Ap = (phase == 2) ? yl : yh;
  const u16* Bp = (phase == 1) ? Bwl : Bwh;

  f32x4 acc[4][4];
#pragma unroll
  for (int i = 0; i < 4; ++i)
#pragma unroll
    for (int j = 0; j < 4; ++j) acc[i][j] = (f32x4){0.f, 0.f, 0.f, 0.f};

  int flat0 = w * 128 + lane;
  int flat1 = flat0 + 64;
  int arow0 = flat0 >> 2, arow1 = flat1 >> 2;
  int aq0 = (flat0 & 3) ^ ((arow0 >> 1) & 3);
  int aq1 = (flat1 & 3) ^ ((arow1 >> 1) & 3);
  int rq = (quad ^ ((lanelo >> 1) & 3)) * 8;

  size_t aoff0 = (size_t)(m0 + arow0) * 256 + aq0 * 8;
  size_t aoff1 = (size_t)(m0 + arow1) * 256 + aq1 * 8;
  size_t boff0 = (size_t)(n0 + arow0) * 32 + aq0 * 8;
  size_t boff1 = (size_t)(n0 + arow1) * 32 + aq1 * 8;
  int posy_base = 2 * ph * 20 + 2 * pwc;

  for (int kh = seg * 3; kh < seg * 3 + 3; ++kh) {
    for (int kw = 0; kw < 9; ++kw) {
      int posy = posy_base + kh * 20 + kw;
      const u16* Abase = Ap + (size_t)posy * 65536;
      const u16* Bbase = Bp + (size_t)((kh * 9 + kw) * 8) * 8192;
      for (int icb = 0; icb < 8; ++icb) {
        __syncthreads();
        load_lds16(Abase + aoff0 + icb * 32, &As[w * 1024]);
        load_lds16(Abase + aoff1 + icb * 32, &As[w * 1024 + 512]);
        load_lds16(Bbase + (size_t)icb * 8192 + boff0, &Bs[w * 1024]);
        load_lds16(Bbase + (size_t)icb * 8192 + boff1, &Bs[w * 1024 + 512]);
        __syncthreads();
        bf16x8 af[4], bf[4];
#pragma unroll
        for (int fm = 0; fm < 4; ++fm)
          af[fm] = *(const bf16x8*)&As[(mw + fm * 16 + lanelo) * 32 + rq];
#pragma unroll
        for (int fn = 0; fn < 4; ++fn)
          bf[fn] = *(const bf16x8*)&Bs[(nw + fn * 16 + lanelo) * 32 + rq];
#pragma unroll
        for (int fm = 0; fm < 4; ++fm)
#pragma unroll
          for (int fn = 0; fn < 4; ++fn)
            acc[fm][fn] = __builtin_amdgcn_mfma_f32_16x16x32_bf16(
                af[fm], bf[fn], acc[fm][fn], 0, 0, 0);
      }
    }
  }
#pragma unroll
  for (int fm = 0; fm < 4; ++fm) {
    int brow = m0 + mw + fm * 16 + quad * 4;
#pragma unroll
    for (int fn = 0; fn < 4; ++fn) {
      int col = n0 + nw + fn * 16 + lanelo;
#pragma unroll
      for (int r = 0; r < 4; ++r)
        atomicAdd(&praw2[((size_t)p * 256 + brow + r) * 256 + col],
                  acc[fm][fn][r]);
    }
  }
}

// ======= k_route: cooperative mega-kernel — squash + routing + decoder =======
// grid 256 x 256. LDS union 13824 floats (54 KB).
__global__ __launch_bounds__(256)
void k_route(const float* __restrict__ praw2, float* __restrict__ u,
             const float* __restrict__ W, float* __restrict__ bij,
             float* __restrict__ s, float* __restrict__ varr,
             float* __restrict__ out_v, float* __restrict__ out_m,
             const float* __restrict__ dw1, const float* __restrict__ db1,
             const float* __restrict__ dw2, const float* __restrict__ db2,
             const float* __restrict__ dw3, const float* __restrict__ db3,
             float* __restrict__ h2, float* __restrict__ out_rec,
             int* __restrict__ idxA) {
  cg::grid_group grid = cg::this_grid();
  __shared__ __align__(16) float smem[13824];
  int bx = blockIdx.x, t = threadIdx.x;
  int lane = t & 63, w = t >> 6;

  // ---- stage 0: squash-transpose praw2[p][b][oc] -> u[b][oc*36+p] (4 units)
  {
    float* st = smem;  // 36*65 = 2340
    for (int un = 0; un < 4; ++un) {
      int unit = bx * 4 + un;
      int oc0 = (unit & 3) * 64, b = unit >> 2;
      __syncthreads();
#pragma unroll
      for (int j = 0; j < 9; ++j) {
        int e = j * 256 + t;
        int p = e >> 6, ocl = e & 63;
        st[p * 65 + ocl] = praw2[(size_t)p * 65536 + b * 256 + oc0 + ocl];
      }
      __syncthreads();
      float* ub = u + (size_t)b * 9216 + oc0 * 36;
#pragma unroll
      for (int pass = 0; pass < 2; ++pass) {
        int g = pass * 256 + t;
        if (g < 288) {
          int fl = g * 8;
          float vals[8];
          float sn = 0.f;
#pragma unroll
          for (int e = 0; e < 8; ++e) {
            int f = fl + e;
            int ocl = f / 36, p = f - ocl * 36;
            float xx = st[p * 65 + ocl];
            vals[e] = xx;
            sn = fmaf(xx, xx, sn);
          }
          float sc = sn / ((1.f + sn) * sqrtf(sn));
          float4 w0 = {vals[0] * sc, vals[1] * sc, vals[2] * sc, vals[3] * sc};
          float4 w1v = {vals[4] * sc, vals[5] * sc, vals[6] * sc, vals[7] * sc};
          *(float4*)&ub[fl] = w0;
          *(float4*)&ub[fl + 4] = w1v;
        }
      }
    }
  }
  grid.sync();

  // ---- routing iterations
  for (int it = 0; it < 3; ++it) {
    // stage AB: redundant softmax(b_ij) + s-GEMM (32 ksplit x 8 bgroup)
    {
      float* wred = smem;         // 40
      float* u_t = smem + 48;     // 544 (32*17)
      float* w_t = smem + 592;    // 2560
      float* cijl = smem + 3152;  // 360
      int nr = (t < 128) ? 5 : 4;
      float bv[5][10];
      float pm[10];
#pragma unroll
      for (int c = 0; c < 10; ++c) pm[c] = -3.0e38f;
      for (int i = 0; i < nr; ++i) {
        const float* row = bij + (t + i * 256) * 10;
#pragma unroll
        for (int c = 0; c < 10; ++c) {
          bv[i][c] = row[c];
          pm[c] = fmaxf(pm[c], bv[i][c]);
        }
      }
#pragma unroll
      for (int off = 32; off > 0; off >>= 1)
#pragma unroll
        for (int c = 0; c < 10; ++c)
          pm[c] = fmaxf(pm[c], __shfl_xor(pm[c], off));
      if (lane == 0)
#pragma unroll
        for (int c = 0; c < 10; ++c) wred[w * 10 + c] = pm[c];
      __syncthreads();
      float M[10];
#pragma unroll
      for (int c = 0; c < 10; ++c)
        M[c] = fmaxf(fmaxf(wred[0 * 10 + c], wred[1 * 10 + c]),
                     fmaxf(wred[2 * 10 + c], wred[3 * 10 + c]));
      float psum[10];
#pragma unroll
      for (int c = 0; c < 10; ++c) psum[c] = 0.f;
      for (int i = 0; i < nr; ++i)
#pragma unroll
        for (int c = 0; c < 10; ++c) psum[c] += expf(bv[i][c] - M[c]);
#pragma unroll
      for (int off = 32; off > 0; off >>= 1)
#pragma unroll
        for (int c = 0; c < 10; ++c) psum[c] += __shfl_xor(psum[c], off);
      __syncthreads();
      if (lane == 0)
#pragma unroll
        for (int c = 0; c < 10; ++c) wred[w * 10 + c] = psum[c];
      __syncthreads();
      float S[10];
#pragma unroll
      for (int c = 0; c < 10; ++c)
        S[c] = (wred[0 * 10 + c] + wred[1 * 10 + c]) +
               (wred[2 * 10 + c] + wred[3 * 10 + c]);
      int ksp = bx & 31, bgp = bx >> 5;
      int r0 = ksp * 36;
      for (int e = t; e < 360; e += 256) {
        int rl = e / 10, c = e - rl * 10;
        cijl[e] = expf(bij[(r0 + rl) * 10 + c] - M[c]) / S[c];
      }
      int k0 = r0 * 8;
      int b0 = bgp * 32;
      int bg = t >> 4, cog = t & 15;
      int co_base = cog * 10;
      int kk = t >> 4, rr = kk >> 3, ii = kk & 7;
      float acc[2][10];
#pragma unroll
      for (int q = 0; q < 2; ++q)
#pragma unroll
        for (int j = 0; j < 10; ++j) acc[q][j] = 0.f;
      for (int ks2 = 0; ks2 < 18; ++ks2) {
        __syncthreads();
        if (t < 128) {
          int bb = t >> 2, c4 = (t & 3) * 4;
          float4 uv =
              *(const float4*)&u[(size_t)(b0 + bb) * 9216 + k0 + ks2 * 16 + c4];
          u_t[bb * 17 + c4 + 0] = uv.x;
          u_t[bb * 17 + c4 + 1] = uv.y;
          u_t[bb * 17 + c4 + 2] = uv.z;
          u_t[bb * 17 + c4 + 3] = uv.w;
        }
        {
          int r = r0 + ks2 * 2 + rr;
          const float* Wrow = W + (size_t)(r * 10) * 128;
#pragma unroll
          for (int j = 0; j < 10; ++j) {
            int co = co_base + j;
            int c = co >> 4, o = co & 15;
            w_t[kk * 160 + co] =
                cijl[(ks2 * 2 + rr) * 10 + c] * Wrow[c * 128 + o * 8 + ii];
          }
        }
        __syncthreads();
#pragma unroll 4
        for (int k2 = 0; k2 < 16; ++k2) {
          float uq[2];
#pragma unroll
          for (int q = 0; q < 2; ++q) uq[q] = u_t[(bg * 2 + q) * 17 + k2];
#pragma unroll
          for (int j = 0; j < 10; ++j) {
            float wv = w_t[k2 * 160 + co_base + j];
#pragma unroll
            for (int q = 0; q < 2; ++q) acc[q][j] = fmaf(uq[q], wv, acc[q][j]);
          }
        }
      }
#pragma unroll
      for (int q = 0; q < 2; ++q)
#pragma unroll
        for (int j = 0; j < 10; ++j)
          atomicAdd(&s[(b0 + bg * 2 + q) * 160 + co_base + j], acc[q][j]);
    }
    grid.sync();
    // stage C: v = squash(s) elementwise; re-zero s; final iter -> out_v
    if (t < 160) {
      int e = bx * 160 + t;
      float xx = s[e];
      s[e] = 0.f;
      float sn = xx * xx;
      float val = sn * xx / ((1.f + sn) * sqrtf(sn));
      varr[e] = val;
      if (it == 2) out_v[e] = val;
    }
    grid.sync();
    if (it < 2) {
      // stage D: agreement M-tile + bij update (blocks 0..143)
      if (bx < 144) {
        float* u_c = smem;          // 1024
        float* v_c = smem + 1024;   // 2560
        float* Ms = smem + 3584;    // 10240
        int ri0 = bx * 64;
        int rig = t >> 4, cog = t & 15;
        float acc[4][10];
#pragma unroll
        for (int q = 0; q < 4; ++q)
#pragma unroll
          for (int j = 0; j < 10; ++j) acc[q][j] = 0.f;
        for (int bc = 0; bc < 16; ++bc) {
          __syncthreads();
          {
            int bb = t >> 4, c4 = t & 15;
            *(float4*)&u_c[(bb * 16 + c4) * 4] =
                *(const float4*)&u[(size_t)(bc * 16 + bb) * 9216 + ri0 + c4 * 4];
          }
          const float* vsl = varr + bc * 16 * 160;
#pragma unroll
          for (int j = 0; j < 10; ++j) v_c[t + 256 * j] = vsl[t + 256 * j];
          __syncthreads();
#pragma unroll 4
          for (int bb = 0; bb < 16; ++bb) {
            float uq[4];
#pragma unroll
            for (int q = 0; q < 4; ++q) uq[q] = u_c[bb * 64 + rig * 4 + q];
#pragma unroll
            for (int j = 0; j < 10; ++j) {
              float vv = v_c[bb * 160 + cog * 10 + j];
#pragma unroll
              for (int q = 0; q < 4; ++q)
                acc[q][j] = fmaf(uq[q], vv, acc[q][j]);
            }
          }
        }
        __syncthreads();
#pragma unroll
        for (int q = 0; q < 4; ++q)
#pragma unroll
          for (int j = 0; j < 10; ++j)
            Ms[(rig * 4 + q) * 160 + cog * 10 + j] = acc[q][j];
        __syncthreads();
        if (t < 80) {
          int rl = t / 10, c = t - rl * 10;
          int r = bx * 8 + rl;
          const float* Wb = W + ((size_t)(r * 10 + c)) * 128;
          float dot = 0.f;
#pragma unroll
          for (int i = 0; i < 8; ++i)
#pragma unroll
            for (int o = 0; o < 16; ++o)
              dot = fmaf(Wb[o * 8 + i], Ms[(rl * 8 + i) * 160 + c * 16 + o],
                         dot);
          bij[r * 10 + c] += dot * (1.f / 256.f);
        }
      }
      grid.sync();
    }
  }

  // ---- stage E1: class norms + batch-softmax + argmax + mask (block 0)
  if (bx == 0) {
    float* red = smem;
    float* Msh = smem + 256;
    float* Ssh = smem + 272;
    float nrm[10];
#pragma unroll
    for (int c = 0; c < 10; ++c) {
      float sn = 0.f;
#pragma unroll
      for (int o = 0; o < 16; ++o) {
        float xx = varr[t * 160 + c * 16 + o];
        sn = fmaf(xx, xx, sn);
      }
      nrm[c] = sqrtf(sn);
    }
    for (int c = 0; c < 10; ++c) {
      red[t] = nrm[c];
      __syncthreads();
      for (int sred = 128; sred > 0; sred >>= 1) {
        if (t < sred) red[t] = fmaxf(red[t], red[t + sred]);
        __syncthreads();
      }
      if (t == 0) Msh[c] = red[0];
      __syncthreads();
      red[t] = expf(nrm[c] - Msh[c]);
      __syncthreads();
      for (int sred = 128; sred > 0; sred >>= 1) {
        if (t < sred) red[t] += red[t + sred];
        __syncthreads();
      }
      if (t == 0) Ssh[c] = red[0];
      __syncthreads();
    }
    int best = 0;
    float bvv = expf(nrm[0] - Msh[0]) / Ssh[0];
#pragma unroll
    for (int c = 1; c < 10; ++c) {
      float p = expf(nrm[c] - Msh[c]) / Ssh[c];
      if (p > bvv) { bvv = p; best = c; }
    }
    idxA[t] = best;
#pragma unroll
    for (int c = 0; c < 10; ++c) out_m[t * 10 + c] = (c == best) ? 1.f : 0.f;
  }
  grid.sync();

  // ---- stage E2: fc1+fc2 (blocks 0..127: 4 n-tiles x 32 b-groups of 8)
  if (bx < 128) {
    float* hl = smem;  // 4096
    int nt = bx & 3;
    int b0 = (bx >> 2) * 8;
    for (int e = t; e < 4096; e += 256) {
      int bb = e >> 9, n = e & 511;
      int b = b0 + bb;
      int ii = idxA[b];
      float a = db1[n];
#pragma unroll
      for (int o = 0; o < 16; ++o)
        a = fmaf(varr[b * 160 + ii * 16 + o],
                 dw1[(size_t)(ii * 16 + o) * 512 + n], a);
      hl[bb * 512 + n] = fmaxf(a, 0.f);
    }
    __syncthreads();
    int n = nt * 256 + t;
    float bias = db2[n];
    float acc[8];
#pragma unroll
    for (int bb = 0; bb < 8; ++bb) acc[bb] = bias;
    for (int k = 0; k < 512; ++k) {
      float wv = dw2[(size_t)k * 1024 + n];
#pragma unroll
      for (int bb = 0; bb < 8; ++bb)
        acc[bb] = fmaf(hl[bb * 512 + k], wv, acc[bb]);
    }
#pragma unroll
    for (int bb = 0; bb < 8; ++bb)
      h2[(size_t)(b0 + bb) * 1024 + n] = fmaxf(acc[bb], 0.f);
  }
  grid.sync();

  // ---- stage E3: fc3 + sigmoid (all 256 blocks: 4 n-tiles x 64 b-groups of 4)
  {
    float* hl = smem;  // 4096
    int nt = bx & 3;
    int b0 = (bx >> 2) * 4;
    const float* src = h2 + (size_t)b0 * 1024;
    __syncthreads();
#pragma unroll
    for (int j = 0; j < 16; ++j) hl[t + 256 * j] = src[t + 256 * j];
    __syncthreads();
    int n = nt * 256 + t;
    if (n < 784) {
      float bias = db3[n];
      float acc[4];
#pragma unroll
      for (int bb = 0; bb < 4; ++bb) acc[bb] = bias;
      for (int k = 0; k < 1024; ++k) {
        float wv = dw3[(size_t)k * 784 + n];
#pragma unroll
        for (int bb = 0; bb < 4; ++bb)
          acc[bb] = fmaf(hl[bb * 1024 + k], wv, acc[bb]);
      }
#pragma unroll
      for (int bb = 0; bb < 4; ++bb)
        out_rec[(size_t)(b0 + bb) * 784 + n] = 1.f / (1.f + expf(-acc[bb]));
    }
  }
}

extern "C" void kernel_launch(void* const* d_in, const int* in_sizes, int n_in,
                              void* d_out, int out_size, void* d_ws, size_t ws_size,
                              hipStream_t stream) {
  const float* x   = (const float*)d_in[0];
  const float* c1w = (const float*)d_in[1];
  const float* c1b = (const float*)d_in[2];
  const float* pw  = (const float*)d_in[3];
  const float* Wc  = (const float*)d_in[5];
  const float* dw1 = (const float*)d_in[6];
  const float* db1 = (const float*)d_in[7];
  const float* dw2 = (const float*)d_in[8];
  const float* db2 = (const float*)d_in[9];
  const float* dw3 = (const float*)d_in[10];
  const float* db3 = (const float*)d_in[11];
  float* out = (float*)d_out;
  float* wsf = (float*)d_ws;

  // workspace layout (float units)
  u16* Bwh     = (u16*)(wsf + 0);          // 2,654,208 f
  u16* Bwl     = (u16*)(wsf + 2654208);    // 2,654,208 f
  u16* yh      = (u16*)(wsf + 5308416);    // 13,107,200 f
  u16* yl      = (u16*)(wsf + 18415616);   // 13,107,200 f
  float* praw2 = wsf + 31522816;           // 2,359,296
  float* u     = wsf + 33882112;           // 2,359,296
  float* bij   = wsf + 36241408;           // 11,520 (contiguous with sarr)
  float* sarr  = wsf + 36252928;           // 40,960
  float* varr  = wsf + 36293888;           // 40,960
  float* h2    = wsf + 36334848;           // 262,144
  int*   idxA  = (int*)(wsf + 36596992);   // 256

  float* out_v   = out + 200704;
  float* out_rec = out + 241664;
  float* out_m   = out + 442368;

  k_setup<<<5112, 256, 0, stream>>>(x, out, praw2, bij, pw, Bwh, Bwl, c1w, c1b,
                                    yh, yl);
  k_mfma<<<dim3(36, 36), 256, 0, stream>>>(yh, yl, Bwh, Bwl, praw2);

  void* args[] = {&praw2, &u,   &Wc,  &bij, &sarr, &varr, &out_v, &out_m, &dw1,
                  &db1,   &dw2, &db2, &dw3, &db3,  &h2,   &out_rec, &idxA};
  hipLaunchCooperativeKernel((void*)k_route, dim3(256), dim3(256), args, 0,
                             stream);
}

// Round 8
// 1260.366 us; speedup vs baseline: 1.0967x; 1.0967x over previous
//
#include <hip/hip_runtime.h>
#include <math.h>

#define NB 256
#define NR 1152

typedef unsigned short u16;
typedef __bf16 bf16x8 __attribute__((ext_vector_type(8)));
typedef float f32x4 __attribute__((ext_vector_type(4)));

__device__ __forceinline__ void load_lds16(const void* g, void* l) {
  __builtin_amdgcn_global_load_lds(
      (const __attribute__((address_space(1))) void*)g,
      (__attribute__((address_space(3))) void*)l, 16, 0, 0);
}

__device__ __forceinline__ u16 bf16_rn(float f) {
  unsigned u = __float_as_uint(f);
  unsigned r = (u + 0x7fffu + ((u >> 16) & 1u)) >> 16;
  return (u16)r;
}

// ================= k_setup: fused init + prep_w + conv1 =================
// [0,196): copy x->out | [196,2500): zero praw2 | [2500,2563): zero bij/cij/sarr
// [2563,4611): weight repack | [4611,5123): conv1
__global__ __launch_bounds__(256)
void k_setup(const float* __restrict__ x, float* __restrict__ out,
             float* __restrict__ praw2, float* __restrict__ bijz,
             const float* __restrict__ pw, u16* __restrict__ Bwh,
             u16* __restrict__ Bwl, const float* __restrict__ w1,
             const float* __restrict__ b1, u16* __restrict__ yh,
             u16* __restrict__ yl) {
  __shared__ __align__(16) float smem[6016];
  int bid = blockIdx.x, t = threadIdx.x;
  float4 z = {0.f, 0.f, 0.f, 0.f};
  if (bid < 196) {
    ((float4*)out)[bid * 256 + t] = ((const float4*)x)[bid * 256 + t];
  } else if (bid < 2500) {
    ((float4*)praw2)[(bid - 196) * 256 + t] = z;
  } else if (bid < 2563) {
    int i = (bid - 2500) * 256 + t;
    if (i < 16000) ((float4*)bijz)[i] = z;
  } else if (bid < 4611) {
    float* ld = smem;
    int q = bid - 2563;
    int icb = q & 7, oc = q >> 3;
    const float* src = pw + ((size_t)oc * 256 + icb * 32) * 81;
    for (int j = t; j < 2592; j += 256) ld[j] = src[j];
    __syncthreads();
    for (int j = t; j < 2592; j += 256) {
      int tap = j >> 5, icl = j & 31;
      float v = ld[icl * 81 + tap];
      u16 h = bf16_rn(v);
      float hf = __uint_as_float(((unsigned)h) << 16);
      u16 l = bf16_rn(v - hf);
      size_t o = ((size_t)(tap * 8 + icb) * 256 + oc) * 32 + icl;
      Bwh[o] = h;
      Bwl[o] = l;
    }
  } else {
    float* x_lds = smem;        // 896
    float* yt = smem + 896;     // 5120
    int q = bid - 4611;
    int icc = q & 1, b = q >> 1;
    for (int j = t; j < 784; j += 256)
      x_lds[(j / 28) * 32 + (j % 28)] = x[b * 784 + j];
    if (t < 112) x_lds[(t >> 2) * 32 + 28 + (t & 3)] = 0.f;
    int icl = t & 127, half = t >> 7;
    int ic = icc * 128 + icl;
    float bias = b1[ic];
    float wreg[81];
#pragma unroll
    for (int j = 0; j < 81; ++j) wreg[j] = w1[ic * 81 + j];
    __syncthreads();
    for (int r0 = 0; r0 < 10; ++r0) {
      int row = half * 10 + r0;
      float vout[20];
#pragma unroll
      for (int seg = 0; seg < 3; ++seg) {
        const int c0 = (seg == 0) ? 0 : (seg == 1 ? 8 : 16);
        const int W = (seg == 2) ? 4 : 8;
        float a[8];
#pragma unroll
        for (int i = 0; i < 8; ++i) a[i] = bias;
#pragma unroll
        for (int kh = 0; kh < 9; ++kh) {
          float xv[16];
          const float* xr = &x_lds[(row + kh) * 32 + c0];
          *(float4*)&xv[0] = *(const float4*)&xr[0];
          *(float4*)&xv[4] = *(const float4*)&xr[4];
          *(float4*)&xv[8] = *(const float4*)&xr[8];
          *(float4*)&xv[12] = *(const float4*)&xr[12];
#pragma unroll
          for (int kw = 0; kw < 9; ++kw) {
            float wv = wreg[kh * 9 + kw];
#pragma unroll
            for (int i = 0; i < W; ++i) a[i] = fmaf(xv[i + kw], wv, a[i]);
          }
        }
#pragma unroll
        for (int i = 0; i < W; ++i) vout[c0 + i] = fmaxf(a[i], 0.f);
      }
#pragma unroll
      for (int c = 0; c < 20; ++c) yt[half * 2560 + c * 128 + icl] = vout[c];
      __syncthreads();
#pragma unroll
      for (int j = 0; j < 20; ++j) {
        int idx = j * 2 + half;
        int hh = (idx >= 20) ? 1 : 0;
        int cc = idx - hh * 20;
        float v = yt[hh * 2560 + cc * 128 + icl];
        int rw = hh * 10 + r0;
        u16 h = bf16_rn(v);
        float hf = __uint_as_float(((unsigned)h) << 16);
        u16 l = bf16_rn(v - hf);
        size_t o = ((size_t)(rw * 20 + cc) * 256 + b) * 256 + icc * 128 + icl;
        yh[o] = h;
        yl[o] = l;
      }
      __syncthreads();
    }
  }
}

// ===== MFMA implicit GEMM: 2-p merge + ping-pong dbuf, 1 barrier/step =====
// grid (36, 18 px): bx = mt(1b) nt(1b) ks(0..8); ks -> phase(3) x kh-seg(3)
__global__ __launch_bounds__(256)
void k_mfma(const u16* __restrict__ yh, const u16* __restrict__ yl,
            const u16* __restrict__ Bwh, const u16* __restrict__ Bwl,
            float* __restrict__ praw2) {
  __shared__ __align__(16) u16 As0[8192];  // [buf][4096]
  __shared__ __align__(16) u16 As1[8192];
  __shared__ __align__(16) u16 Bs[8192];
  int t = threadIdx.x;
  int lane = t & 63, w = t >> 6;
  int lanelo = lane & 15, quad = lane >> 4;
  int bx = blockIdx.x;
  int mt = bx & 1, nt = (bx >> 1) & 1, ks = bx >> 2;
  int phase = ks / 3, seg = ks - phase * 3;
  int m0 = mt * 128, n0 = nt * 128;
  int px = blockIdx.y;
  int p0 = 2 * px, p1 = p0 + 1;
  int ph = p0 / 6, pwc = p0 - ph * 6;
  int mw = (w & 1) * 64, nw = (w >> 1) * 64;
  const u16* Ap = (phase == 2) ? yl : yh;
  const u16* Bp = (phase == 1) ? Bwl : Bwh;

  f32x4 acc0[4][4], acc1[4][4];
#pragma unroll
  for (int i = 0; i < 4; ++i)
#pragma unroll
    for (int j = 0; j < 4; ++j) {
      acc0[i][j] = (f32x4){0.f, 0.f, 0.f, 0.f};
      acc1[i][j] = (f32x4){0.f, 0.f, 0.f, 0.f};
    }

  int flat0 = w * 128 + lane;
  int flat1 = flat0 + 64;
  int arow0 = flat0 >> 2, arow1 = flat1 >> 2;
  int aq0 = (flat0 & 3) ^ ((arow0 >> 1) & 3);  // store-side XOR swizzle
  int aq1 = (flat1 & 3) ^ ((arow1 >> 1) & 3);
  int rq = (quad ^ ((lanelo >> 1) & 3)) * 8;   // read-side matching swizzle

  size_t aoff0 = (size_t)(m0 + arow0) * 256 + aq0 * 8;
  size_t aoff1 = (size_t)(m0 + arow1) * 256 + aq1 * 8;
  size_t boff0 = (size_t)(n0 + arow0) * 32 + aq0 * 8;
  size_t boff1 = (size_t)(n0 + arow1) * 32 + aq1 * 8;
  int posy_base = (2 * ph + seg * 3) * 20 + 2 * pwc;
  int ldst0 = w * 1024, ldst1 = w * 1024 + 512;

  // issue DMA for step qn into buffer (qn&1)
  auto issue = [&](int qn) {
    int tap = qn >> 3, icb = qn & 7;
    int khh = tap / 9;
    int kww = tap - khh * 9;
    int posy = posy_base + khh * 20 + kww;
    const u16* A0 = Ap + (size_t)posy * 65536 + icb * 32;
    const u16* Bb = Bp + ((size_t)((seg * 3 + khh) * 9 + kww) * 8 +
                          (size_t)icb) * 8192;
    int bo = (qn & 1) * 4096;
    load_lds16(A0 + aoff0, &As0[bo + ldst0]);
    load_lds16(A0 + aoff1, &As0[bo + ldst1]);
    load_lds16(A0 + 2 * 65536 + aoff0, &As1[bo + ldst0]);
    load_lds16(A0 + 2 * 65536 + aoff1, &As1[bo + ldst1]);
    load_lds16(Bb + boff0, &Bs[bo + ldst0]);
    load_lds16(Bb + boff1, &Bs[bo + ldst1]);
  };

  issue(0);
#pragma unroll 1
  for (int q = 0; q < 216; ++q) {
    __syncthreads();             // drains DMA for buf (q&1); frees other buf
    if (q < 215) issue(q + 1);   // overlaps with compute below
    int bo = (q & 1) * 4096;
    bf16x8 bfv[4], afv[4];
#pragma unroll
    for (int fn = 0; fn < 4; ++fn)
      bfv[fn] = *(const bf16x8*)&Bs[bo + (nw + fn * 16 + lanelo) * 32 + rq];
#pragma unroll
    for (int fm = 0; fm < 4; ++fm)
      afv[fm] = *(const bf16x8*)&As0[bo + (mw + fm * 16 + lanelo) * 32 + rq];
#pragma unroll
    for (int fm = 0; fm < 4; ++fm)
#pragma unroll
      for (int fn = 0; fn < 4; ++fn)
        acc0[fm][fn] = __builtin_amdgcn_mfma_f32_16x16x32_bf16(
            afv[fm], bfv[fn], acc0[fm][fn], 0, 0, 0);
#pragma unroll
    for (int fm = 0; fm < 4; ++fm)
      afv[fm] = *(const bf16x8*)&As1[bo + (mw + fm * 16 + lanelo) * 32 + rq];
#pragma unroll
    for (int fm = 0; fm < 4; ++fm)
#pragma unroll
      for (int fn = 0; fn < 4; ++fn)
        acc1[fm][fn] = __builtin_amdgcn_mfma_f32_16x16x32_bf16(
            afv[fm], bfv[fn], acc1[fm][fn], 0, 0, 0);
  }
#pragma unroll
  for (int fm = 0; fm < 4; ++fm) {
    int brow = m0 + mw + fm * 16 + quad * 4;
#pragma unroll
    for (int fn = 0; fn < 4; ++fn) {
      int col = n0 + nw + fn * 16 + lanelo;
#pragma unroll
      for (int r = 0; r < 4; ++r) {
        atomicAdd(&praw2[((size_t)p0 * 256 + brow + r) * 256 + col],
                  acc0[fm][fn][r]);
        atomicAdd(&praw2[((size_t)p1 * 256 + brow + r) * 256 + col],
                  acc1[fm][fn][r]);
      }
    }
  }
}

// ---------- squash: tiled transpose praw2[p][b][oc] -> u[b][oc*36+p]
__global__ __launch_bounds__(256)
void k_squash2(const float* __restrict__ praw2, float* __restrict__ u) {
  __shared__ float st[36 * 65];
  int t = threadIdx.x;
  int oc0 = blockIdx.x * 64, b = blockIdx.y;
#pragma unroll
  for (int j = 0; j < 9; ++j) {
    int e = j * 256 + t;
    int p = e >> 6, ocl = e & 63;
    st[p * 65 + ocl] = praw2[(size_t)p * 65536 + b * 256 + oc0 + ocl];
  }
  __syncthreads();
  float* ub = u + (size_t)b * 9216 + oc0 * 36;
#pragma unroll
  for (int pass = 0; pass < 2; ++pass) {
    int g = pass * 256 + t;
    if (g < 288) {
      int fl = g * 8;
      float vals[8];
      float sn = 0.f;
#pragma unroll
      for (int e = 0; e < 8; ++e) {
        int f = fl + e;
        int ocl = f / 36, p = f - ocl * 36;
        float xx = st[p * 65 + ocl];
        vals[e] = xx;
        sn = fmaf(xx, xx, sn);
      }
      float sc = sn / ((1.f + sn) * sqrtf(sn));
      float4 w0 = {vals[0] * sc, vals[1] * sc, vals[2] * sc, vals[3] * sc};
      float4 w1 = {vals[4] * sc, vals[5] * sc, vals[6] * sc, vals[7] * sc};
      *(float4*)&ub[fl] = w0;
      *(float4*)&ub[fl + 4] = w1;
    }
  }
}

// ---------- softmax of b_ij over routes per class (blocks 0..9) + zero sarr
__global__ __launch_bounds__(256)
void k_softmax(const float* __restrict__ bij, float* __restrict__ cij,
               float* __restrict__ sarr) {
  int t = threadIdx.x;
  if (blockIdx.x >= 10) {
    int base = (blockIdx.x - 10) * 1024 + t;
#pragma unroll
    for (int j = 0; j < 4; ++j) sarr[base + j * 256] = 0.f;
    return;
  }
  __shared__ float red[256];
  int c = blockIdx.x;
  float m = -1e30f;
  for (int r = t; r < NR; r += 256) m = fmaxf(m, bij[r * 10 + c]);
  red[t] = m;
  __syncthreads();
  for (int s = 128; s > 0; s >>= 1) {
    if (t < s) red[t] = fmaxf(red[t], red[t + s]);
    __syncthreads();
  }
  float M = red[0];
  __syncthreads();
  float sm = 0.f;
  for (int r = t; r < NR; r += 256) sm += expf(bij[r * 10 + c] - M);
  red[t] = sm;
  __syncthreads();
  for (int s = 128; s > 0; s >>= 1) {
    if (t < s) red[t] += red[t + s];
    __syncthreads();
  }
  float S = red[0];
  for (int r = t; r < NR; r += 256) cij[r * 10 + c] = expf(bij[r * 10 + c] - M) / S;
}

// ---------- s[b,co] += u[b,:] @ (cij*W)[:,co], W scaled in-LDS
// grid (36 k-split, 8 b-groups of 32)
__global__ __launch_bounds__(256)
void k_s(const float* __restrict__ u, const float* __restrict__ W,
         const float* __restrict__ cij, float* __restrict__ s) {
  __shared__ float u_t[32 * 17];
  __shared__ float w_t[16 * 160];
  __shared__ float cij_l[320];
  int t = threadIdx.x;
  int k0 = blockIdx.x * 256;
  int b0 = blockIdx.y * 32;
  int r0 = k0 >> 3;
  for (int e = t; e < 320; e += 256) cij_l[e] = cij[r0 * 10 + e];
  int bg = t >> 4, cog = t & 15;
  int co_base = cog * 10;
  int kk = t >> 4, rr = kk >> 3, ii = kk & 7;
  float acc[2][10];
#pragma unroll
  for (int q = 0; q < 2; ++q)
#pragma unroll
    for (int j = 0; j < 10; ++j) acc[q][j] = 0.f;

  for (int ks2 = 0; ks2 < 16; ++ks2) {
    __syncthreads();
    if (t < 128) {
      int bb = t >> 2, c4 = (t & 3) * 4;
      float4 uv = *(const float4*)&u[(size_t)(b0 + bb) * 9216 + k0 + ks2 * 16 + c4];
      u_t[bb * 17 + c4 + 0] = uv.x;
      u_t[bb * 17 + c4 + 1] = uv.y;
      u_t[bb * 17 + c4 + 2] = uv.z;
      u_t[bb * 17 + c4 + 3] = uv.w;
    }
    {
      int r = r0 + ks2 * 2 + rr;
      const float* Wrow = W + (size_t)(r * 10) * 128;
#pragma unroll
      for (int j = 0; j < 10; ++j) {
        int co = co_base + j;
        int c = co >> 4, o = co & 15;
        w_t[kk * 160 + co] =
            cij_l[(ks2 * 2 + rr) * 10 + c] * Wrow[c * 128 + o * 8 + ii];
      }
    }
    __syncthreads();
#pragma unroll 4
    for (int k2 = 0; k2 < 16; ++k2) {
      float uq[2];
#pragma unroll
      for (int q = 0; q < 2; ++q) uq[q] = u_t[(bg * 2 + q) * 17 + k2];
#pragma unroll
      for (int j = 0; j < 10; ++j) {
        float wv = w_t[k2 * 160 + co_base + j];
#pragma unroll
        for (int q = 0; q < 2; ++q) acc[q][j] = fmaf(uq[q], wv, acc[q][j]);
      }
    }
  }
#pragma unroll
  for (int q = 0; q < 2; ++q)
#pragma unroll
    for (int j = 0; j < 10; ++j)
      atomicAdd(&s[(b0 + bg * 2 + q) * 160 + co_base + j], acc[q][j]);
}

// ---------- elementwise squash (faithful quirk) s -> v, also to out
__global__ __launch_bounds__(256)
void k_v(const float* __restrict__ s, float* __restrict__ v,
         float* __restrict__ outv) {
  int e = blockIdx.x * 256 + threadIdx.x;  // 40960
  float xx = s[e];
  float sn = xx * xx;
  float val = sn * xx / ((1.f + sn) * sqrtf(sn));
  v[e] = val;
  outv[e] = val;
}

// ---------- fused agreement: M-tile in LDS then bij update
__global__ __launch_bounds__(256)
void k_Mb(const float* __restrict__ u, const float* __restrict__ v,
          const float* __restrict__ W, float* __restrict__ bij) {
  __shared__ float4 u_c4[16 * 16];
  __shared__ float v_c[16 * 160];
  __shared__ float Ms[64 * 160];
  float* u_c = (float*)u_c4;
  int t = threadIdx.x;
  int ri0 = blockIdx.x * 64;
  int rig = t >> 4, cog = t & 15;
  float acc[4][10];
#pragma unroll
  for (int q = 0; q < 4; ++q)
#pragma unroll
    for (int j = 0; j < 10; ++j) acc[q][j] = 0.f;
  for (int bc = 0; bc < 16; ++bc) {
    __syncthreads();
    {
      int bb = t >> 4, c4 = t & 15;
      u_c4[bb * 16 + c4] =
          *(const float4*)&u[(size_t)(bc * 16 + bb) * 9216 + ri0 + c4 * 4];
    }
    const float* vsl = v + bc * 16 * 160;
#pragma unroll
    for (int j = 0; j < 10; ++j) v_c[t + 256 * j] = vsl[t + 256 * j];
    __syncthreads();
#pragma unroll 4
    for (int bb = 0; bb < 16; ++bb) {
      float uq[4];
#pragma unroll
      for (int q = 0; q < 4; ++q) uq[q] = u_c[bb * 64 + rig * 4 + q];
#pragma unroll
      for (int j = 0; j < 10; ++j) {
        float vv = v_c[bb * 160 + cog * 10 + j];
#pragma unroll
        for (int q = 0; q < 4; ++q) acc[q][j] = fmaf(uq[q], vv, acc[q][j]);
      }
    }
  }
  __syncthreads();
#pragma unroll
  for (int q = 0; q < 4; ++q)
#pragma unroll
    for (int j = 0; j < 10; ++j)
      Ms[(rig * 4 + q) * 160 + cog * 10 + j] = acc[q][j];
  __syncthreads();
  if (t < 80) {
    int rl = t / 10, c = t - rl * 10;
    int r = blockIdx.x * 8 + rl;
    const float* Wb = W + ((size_t)(r * 10 + c)) * 128;
    float dot = 0.f;
#pragma unroll
    for (int i = 0; i < 8; ++i)
#pragma unroll
      for (int o = 0; o < 16; ++o)
        dot = fmaf(Wb[o * 8 + i], Ms[(rl * 8 + i) * 160 + c * 16 + o], dot);
    bij[r * 10 + c] += dot * (1.f / 256.f);
  }
}

// ---------- class norms, softmax over batch, argmax, mask. grid 1
__global__ __launch_bounds__(256)
void k_cls(const float* __restrict__ v, float* __restrict__ outm,
           int* __restrict__ idxA) {
  __shared__ float red[256];
  __shared__ float Ms[10], Ss[10];
  int t = threadIdx.x;  // = b
  float nrm[10];
#pragma unroll
  for (int c = 0; c < 10; ++c) {
    float sn = 0.f;
#pragma unroll
    for (int o = 0; o < 16; ++o) {
      float xx = v[t * 160 + c * 16 + o];
      sn = fmaf(xx, xx, sn);
    }
    nrm[c] = sqrtf(sn);
  }
  for (int c = 0; c < 10; ++c) {
    red[t] = nrm[c];
    __syncthreads();
    for (int s = 128; s > 0; s >>= 1) {
      if (t < s) red[t] = fmaxf(red[t], red[t + s]);
      __syncthreads();
    }
    if (t == 0) Ms[c] = red[0];
    __syncthreads();
    red[t] = expf(nrm[c] - Ms[c]);
    __syncthreads();
    for (int s = 128; s > 0; s >>= 1) {
      if (t < s) red[t] += red[t + s];
      __syncthreads();
    }
    if (t == 0) Ss[c] = red[0];
    __syncthreads();
  }
  int best = 0;
  float bv = expf(nrm[0] - Ms[0]) / Ss[0];
#pragma unroll
  for (int c = 1; c < 10; ++c) {
    float p = expf(nrm[c] - Ms[c]) / Ss[c];
    if (p > bv) { bv = p; best = c; }
  }
  idxA[t] = best;
#pragma unroll
  for (int c = 0; c < 10; ++c) outm[t * 10 + c] = (c == best) ? 1.f : 0.f;
}

// ---------- fused fc1+fc2. grid (4 n-tiles, 32 b-groups of 8)
__global__ __launch_bounds__(256)
void k_fc12(const float* __restrict__ v, const int* __restrict__ idxA,
            const float* __restrict__ w1, const float* __restrict__ b1,
            const float* __restrict__ w2, const float* __restrict__ b2,
            float* __restrict__ h2) {
  __shared__ float hl[8 * 512];
  int t = threadIdx.x;
  int b0 = blockIdx.y * 8;
  for (int e = t; e < 4096; e += 256) {
    int bb = e >> 9, n = e & 511;
    int b = b0 + bb;
    int ii = idxA[b];
    float a = b1[n];
#pragma unroll
    for (int o = 0; o < 16; ++o)
      a = fmaf(v[b * 160 + ii * 16 + o], w1[(size_t)(ii * 16 + o) * 512 + n], a);
    hl[bb * 512 + n] = fmaxf(a, 0.f);
  }
  __syncthreads();
  int n = blockIdx.x * 256 + t;
  float bias = b2[n];
  float acc[8];
#pragma unroll
  for (int bb = 0; bb < 8; ++bb) acc[bb] = bias;
  for (int k = 0; k < 512; ++k) {
    float w = w2[(size_t)k * 1024 + n];
#pragma unroll
    for (int bb = 0; bb < 8; ++bb) acc[bb] = fmaf(hl[bb * 512 + k], w, acc[bb]);
  }
#pragma unroll
  for (int bb = 0; bb < 8; ++bb)
    h2[(size_t)(b0 + bb) * 1024 + n] = fmaxf(acc[bb], 0.f);
}

// ---------- fc3 + sigmoid -> rec. grid (4 n-tiles, 32 b-groups of 8)
__global__ __launch_bounds__(256)
void k_fc3(const float* __restrict__ h2, const float* __restrict__ w3,
           const float* __restrict__ b3, float* __restrict__ rec) {
  __shared__ float hl[8 * 1024];
  int t = threadIdx.x;
  int n = blockIdx.x * 256 + t;
  int b0 = blockIdx.y * 8;
  const float* src = h2 + (size_t)b0 * 1024;
#pragma unroll
  for (int j = 0; j < 32; ++j) hl[t + 256 * j] = src[t + 256 * j];
  __syncthreads();
  if (n < 784) {
    float bias = b3[n];
    float acc[8];
#pragma unroll
    for (int bb = 0; bb < 8; ++bb) acc[bb] = bias;
    for (int k = 0; k < 1024; ++k) {
      float w = w3[(size_t)k * 784 + n];
#pragma unroll
      for (int bb = 0; bb < 8; ++bb) acc[bb] = fmaf(hl[bb * 1024 + k], w, acc[bb]);
    }
#pragma unroll
    for (int bb = 0; bb < 8; ++bb)
      rec[(size_t)(b0 + bb) * 784 + n] = 1.f / (1.f + expf(-acc[bb]));
  }
}

extern "C" void kernel_launch(void* const* d_in, const int* in_sizes, int n_in,
                              void* d_out, int out_size, void* d_ws, size_t ws_size,
                              hipStream_t stream) {
  const float* x   = (const float*)d_in[0];
  const float* c1w = (const float*)d_in[1];
  const float* c1b = (const float*)d_in[2];
  const float* pw  = (const float*)d_in[3];
  const float* Wc  = (const float*)d_in[5];
  const float* dw1 = (const float*)d_in[6];
  const float* db1 = (const float*)d_in[7];
  const float* dw2 = (const float*)d_in[8];
  const float* db2 = (const float*)d_in[9];
  const float* dw3 = (const float*)d_in[10];
  const float* db3 = (const float*)d_in[11];
  float* out = (float*)d_out;
  float* wsf = (float*)d_ws;

  // workspace layout (float units)
  u16* Bwh     = (u16*)(wsf + 0);          // 2,654,208 f
  u16* Bwl     = (u16*)(wsf + 2654208);    // 2,654,208 f
  u16* yh      = (u16*)(wsf + 5308416);    // 13,107,200 f
  u16* yl      = (u16*)(wsf + 18415616);   // 13,107,200 f
  float* praw2 = wsf + 31522816;           // 2,359,296
  float* u     = wsf + 33882112;           // 2,359,296
  float* bij   = wsf + 36241408;           // 11,520 (contiguous with cij,sarr)
  float* cij   = wsf + 36252928;           // 11,520
  float* sarr  = wsf + 36264448;           // 40,960
  float* varr  = wsf + 36305408;           // 40,960
  float* h2    = wsf + 36346368;           // 262,144
  int*   idxA  = (int*)(wsf + 36608512);   // 256

  float* out_v   = out + 200704;
  float* out_rec = out + 241664;
  float* out_m   = out + 442368;

  k_setup<<<5123, 256, 0, stream>>>(x, out, praw2, bij, pw, Bwh, Bwl, c1w, c1b,
                                    yh, yl);
  k_mfma<<<dim3(36, 18), 256, 0, stream>>>(yh, yl, Bwh, Bwl, praw2);
  k_squash2<<<dim3(4, 256), 256, 0, stream>>>(praw2, u);

  for (int it = 0; it < 3; ++it) {
    k_softmax<<<50, 256, 0, stream>>>(bij, cij, sarr);
    k_s<<<dim3(36, 8), 256, 0, stream>>>(u, Wc, cij, sarr);
    k_v<<<160, 256, 0, stream>>>(sarr, varr, out_v);
    if (it < 2) k_Mb<<<144, 256, 0, stream>>>(u, varr, Wc, bij);
  }

  k_cls<<<1, 256, 0, stream>>>(varr, out_m, idxA);
  k_fc12<<<dim3(4, 32), 256, 0, stream>>>(varr, idxA, dw1, db1, dw2, db2, h2);
  k_fc3<<<dim3(4, 32), 256, 0, stream>>>(h2, dw3, db3, out_rec);
}

// Round 9
// 1187.495 us; speedup vs baseline: 1.1640x; 1.0614x over previous
//
#include <hip/hip_runtime.h>
#include <math.h>

#define NB 256
#define NR 1152

typedef unsigned short u16;
typedef __bf16 bf16x8 __attribute__((ext_vector_type(8)));
typedef float f32x4 __attribute__((ext_vector_type(4)));

__device__ __forceinline__ void load_lds16(const void* g, void* l) {
  __builtin_amdgcn_global_load_lds(
      (const __attribute__((address_space(1))) void*)g,
      (__attribute__((address_space(3))) void*)l, 16, 0, 0);
}

__device__ __forceinline__ u16 bf16_rn(float f) {
  unsigned u = __float_as_uint(f);
  unsigned r = (u + 0x7fffu + ((u >> 16) & 1u)) >> 16;
  return (u16)r;
}

// ================= k_setup: fused init + prep_w + conv1 =================
// [0,196): copy x->out | [196,2500): zero praw2 | [2500,2632): zero bij+s0+s1+s2
// [2632,4680): weight repack | [4680,5192): conv1
__global__ __launch_bounds__(256)
void k_setup(const float* __restrict__ x, float* __restrict__ out,
             float* __restrict__ praw2, float* __restrict__ bijz,
             const float* __restrict__ pw, u16* __restrict__ Bwh,
             u16* __restrict__ Bwl, const float* __restrict__ w1,
             const float* __restrict__ b1, u16* __restrict__ yh,
             u16* __restrict__ yl) {
  __shared__ __align__(16) float smem[6016];
  int bid = blockIdx.x, t = threadIdx.x;
  float4 z = {0.f, 0.f, 0.f, 0.f};
  if (bid < 196) {
    ((float4*)out)[bid * 256 + t] = ((const float4*)x)[bid * 256 + t];
  } else if (bid < 2500) {
    ((float4*)praw2)[(bid - 196) * 256 + t] = z;
  } else if (bid < 2632) {
    int i = (bid - 2500) * 256 + t;
    if (i < 33600) ((float4*)bijz)[i] = z;
  } else if (bid < 4680) {
    float* ld = smem;
    int q = bid - 2632;
    int icb = q & 7, oc = q >> 3;
    const float* src = pw + ((size_t)oc * 256 + icb * 32) * 81;
    for (int j = t; j < 2592; j += 256) ld[j] = src[j];
    __syncthreads();
    for (int j = t; j < 2592; j += 256) {
      int tap = j >> 5, icl = j & 31;
      float v = ld[icl * 81 + tap];
      u16 h = bf16_rn(v);
      float hf = __uint_as_float(((unsigned)h) << 16);
      u16 l = bf16_rn(v - hf);
      size_t o = ((size_t)(tap * 8 + icb) * 256 + oc) * 32 + icl;
      Bwh[o] = h;
      Bwl[o] = l;
    }
  } else {
    float* x_lds = smem;        // 896
    float* yt = smem + 896;     // 5120
    int q = bid - 4680;
    int icc = q & 1, b = q >> 1;
    for (int j = t; j < 784; j += 256)
      x_lds[(j / 28) * 32 + (j % 28)] = x[b * 784 + j];
    if (t < 112) x_lds[(t >> 2) * 32 + 28 + (t & 3)] = 0.f;
    int icl = t & 127, half = t >> 7;
    int ic = icc * 128 + icl;
    float bias = b1[ic];
    float wreg[81];
#pragma unroll
    for (int j = 0; j < 81; ++j) wreg[j] = w1[ic * 81 + j];
    __syncthreads();
    for (int r0 = 0; r0 < 10; ++r0) {
      int row = half * 10 + r0;
      float vout[20];
#pragma unroll
      for (int seg = 0; seg < 3; ++seg) {
        const int c0 = (seg == 0) ? 0 : (seg == 1 ? 8 : 16);
        const int W = (seg == 2) ? 4 : 8;
        float a[8];
#pragma unroll
        for (int i = 0; i < 8; ++i) a[i] = bias;
#pragma unroll
        for (int kh = 0; kh < 9; ++kh) {
          float xv[16];
          const float* xr = &x_lds[(row + kh) * 32 + c0];
          *(float4*)&xv[0] = *(const float4*)&xr[0];
          *(float4*)&xv[4] = *(const float4*)&xr[4];
          *(float4*)&xv[8] = *(const float4*)&xr[8];
          *(float4*)&xv[12] = *(const float4*)&xr[12];
#pragma unroll
          for (int kw = 0; kw < 9; ++kw) {
            float wv = wreg[kh * 9 + kw];
#pragma unroll
            for (int i = 0; i < W; ++i) a[i] = fmaf(xv[i + kw], wv, a[i]);
          }
        }
#pragma unroll
        for (int i = 0; i < W; ++i) vout[c0 + i] = fmaxf(a[i], 0.f);
      }
#pragma unroll
      for (int c = 0; c < 20; ++c) yt[half * 2560 + c * 128 + icl] = vout[c];
      __syncthreads();
#pragma unroll
      for (int j = 0; j < 20; ++j) {
        int idx = j * 2 + half;
        int hh = (idx >= 20) ? 1 : 0;
        int cc = idx - hh * 20;
        float v = yt[hh * 2560 + cc * 128 + icl];
        int rw = hh * 10 + r0;
        u16 h = bf16_rn(v);
        float hf = __uint_as_float(((unsigned)h) << 16);
        u16 l = bf16_rn(v - hf);
        size_t o = ((size_t)(rw * 20 + cc) * 256 + b) * 256 + icc * 128 + icl;
        yh[o] = h;
        yl[o] = l;
      }
      __syncthreads();
    }
  }
}

// ======= MFMA implicit GEMM (R4-exact measured-best: BK=32, 16 KB LDS) =======
// grid (36, 36 p): bx = mt(1b) nt(1b) ks(0..8). phase = ks/3, kh-seg = ks%3
__global__ __launch_bounds__(256)
void k_mfma(const u16* __restrict__ yh, const u16* __restrict__ yl,
            const u16* __restrict__ Bwh, const u16* __restrict__ Bwl,
            float* __restrict__ praw2) {
  __shared__ __align__(16) u16 As[4096];
  __shared__ __align__(16) u16 Bs[4096];
  int t = threadIdx.x;
  int lane = t & 63, w = t >> 6;
  int lanelo = lane & 15, quad = lane >> 4;
  int bx = blockIdx.x;
  int mt = bx & 1, nt = (bx >> 1) & 1, ks = bx >> 2;
  int phase = ks / 3, seg = ks - phase * 3;
  int m0 = mt * 128, n0 = nt * 128;
  int p = blockIdx.y;
  int ph = p / 6, pwc = p - ph * 6;
  int mw = (w & 1) * 64, nw = (w >> 1) * 64;
  const u16* Ap = (phase == 2) ? yl : yh;
  const u16* Bp = (phase == 1) ? Bwl : Bwh;

  f32x4 acc[4][4];
#pragma unroll
  for (int i = 0; i < 4; ++i)
#pragma unroll
    for (int j = 0; j < 4; ++j) acc[i][j] = (f32x4){0.f, 0.f, 0.f, 0.f};

  int flat0 = w * 128 + lane;
  int flat1 = flat0 + 64;
  int arow0 = flat0 >> 2, arow1 = flat1 >> 2;
  int aq0 = (flat0 & 3) ^ ((arow0 >> 1) & 3);   // store-side XOR swizzle
  int aq1 = (flat1 & 3) ^ ((arow1 >> 1) & 3);
  int rq = (quad ^ ((lanelo >> 1) & 3)) * 8;    // read-side matching swizzle

  size_t aoff0 = (size_t)(m0 + arow0) * 256 + aq0 * 8;
  size_t aoff1 = (size_t)(m0 + arow1) * 256 + aq1 * 8;
  size_t boff0 = (size_t)(n0 + arow0) * 32 + aq0 * 8;
  size_t boff1 = (size_t)(n0 + arow1) * 32 + aq1 * 8;
  int posy_base = 2 * ph * 20 + 2 * pwc;

  for (int kh = seg * 3; kh < seg * 3 + 3; ++kh) {
    for (int kw = 0; kw < 9; ++kw) {
      int posy = posy_base + kh * 20 + kw;
      const u16* Abase = Ap + (size_t)posy * 65536;
      const u16* Bbase = Bp + (size_t)((kh * 9 + kw) * 8) * 8192;
      for (int icb = 0; icb < 8; ++icb) {
        __syncthreads();
        load_lds16(Abase + aoff0 + icb * 32, &As[w * 1024]);
        load_lds16(Abase + aoff1 + icb * 32, &As[w * 1024 + 512]);
        load_lds16(Bbase + (size_t)icb * 8192 + boff0, &Bs[w * 1024]);
        load_lds16(Bbase + (size_t)icb * 8192 + boff1, &Bs[w * 1024 + 512]);
        __syncthreads();
        bf16x8 af[4], bf[4];
#pragma unroll
        for (int fm = 0; fm < 4; ++fm)
          af[fm] = *(const bf16x8*)&As[(mw + fm * 16 + lanelo) * 32 + rq];
#pragma unroll
        for (int fn = 0; fn < 4; ++fn)
          bf[fn] = *(const bf16x8*)&Bs[(nw + fn * 16 + lanelo) * 32 + rq];
#pragma unroll
        for (int fm = 0; fm < 4; ++fm)
#pragma unroll
          for (int fn = 0; fn < 4; ++fn)
            acc[fm][fn] = __builtin_amdgcn_mfma_f32_16x16x32_bf16(
                af[fm], bf[fn], acc[fm][fn], 0, 0, 0);
      }
    }
  }
#pragma unroll
  for (int fm = 0; fm < 4; ++fm) {
    int brow = m0 + mw + fm * 16 + quad * 4;
#pragma unroll
    for (int fn = 0; fn < 4; ++fn) {
      int col = n0 + nw + fn * 16 + lanelo;
#pragma unroll
      for (int r = 0; r < 4; ++r)
        atomicAdd(&praw2[((size_t)p * 256 + brow + r) * 256 + col],
                  acc[fm][fn][r]);
    }
  }
}

// ---------- squash: tiled transpose praw2[p][b][oc] -> u[b][oc*36+p]
__global__ __launch_bounds__(256)
void k_squash2(const float* __restrict__ praw2, float* __restrict__ u) {
  __shared__ float st[36 * 65];
  int t = threadIdx.x;
  int oc0 = blockIdx.x * 64, b = blockIdx.y;
#pragma unroll
  for (int j = 0; j < 9; ++j) {
    int e = j * 256 + t;
    int p = e >> 6, ocl = e & 63;
    st[p * 65 + ocl] = praw2[(size_t)p * 65536 + b * 256 + oc0 + ocl];
  }
  __syncthreads();
  float* ub = u + (size_t)b * 9216 + oc0 * 36;
#pragma unroll
  for (int pass = 0; pass < 2; ++pass) {
    int g = pass * 256 + t;
    if (g < 288) {
      int fl = g * 8;
      float vals[8];
      float sn = 0.f;
#pragma unroll
      for (int e = 0; e < 8; ++e) {
        int f = fl + e;
        int ocl = f / 36, p = f - ocl * 36;
        float xx = st[p * 65 + ocl];
        vals[e] = xx;
        sn = fmaf(xx, xx, sn);
      }
      float sc = sn / ((1.f + sn) * sqrtf(sn));
      float4 w0 = {vals[0] * sc, vals[1] * sc, vals[2] * sc, vals[3] * sc};
      float4 w1 = {vals[4] * sc, vals[5] * sc, vals[6] * sc, vals[7] * sc};
      *(float4*)&ub[fl] = w0;
      *(float4*)&ub[fl + 4] = w1;
    }
  }
}

// ---------- k_s: fused softmax(b_ij) + s[b,co] += u @ (cij*W)  (R6-proven)
// grid (36 k-split, 8 b-groups of 32); s pre-zeroed (triple buffer)
__global__ __launch_bounds__(256)
void k_s(const float* __restrict__ u, const float* __restrict__ W,
         const float* __restrict__ bij, float* __restrict__ s) {
  __shared__ float wred[4][10];
  __shared__ float u_t[32 * 17];
  __shared__ float w_t[16 * 160];
  __shared__ float cij_l[320];
  int t = threadIdx.x;
  int lane = t & 63, w = t >> 6;
  int nr = (t < 128) ? 5 : 4;
  float bv[5][10];
  float pm[10];
#pragma unroll
  for (int c = 0; c < 10; ++c) pm[c] = -3.0e38f;
  for (int i = 0; i < nr; ++i) {
    const float* row = bij + (t + i * 256) * 10;
#pragma unroll
    for (int c = 0; c < 10; ++c) {
      bv[i][c] = row[c];
      pm[c] = fmaxf(pm[c], bv[i][c]);
    }
  }
#pragma unroll
  for (int off = 32; off > 0; off >>= 1)
#pragma unroll
    for (int c = 0; c < 10; ++c) pm[c] = fmaxf(pm[c], __shfl_xor(pm[c], off));
  if (lane == 0)
#pragma unroll
    for (int c = 0; c < 10; ++c) wred[w][c] = pm[c];
  __syncthreads();
  float M[10];
#pragma unroll
  for (int c = 0; c < 10; ++c)
    M[c] = fmaxf(fmaxf(wred[0][c], wred[1][c]), fmaxf(wred[2][c], wred[3][c]));
  float psum[10];
#pragma unroll
  for (int c = 0; c < 10; ++c) psum[c] = 0.f;
  for (int i = 0; i < nr; ++i)
#pragma unroll
    for (int c = 0; c < 10; ++c) psum[c] += expf(bv[i][c] - M[c]);
#pragma unroll
  for (int off = 32; off > 0; off >>= 1)
#pragma unroll
    for (int c = 0; c < 10; ++c) psum[c] += __shfl_xor(psum[c], off);
  __syncthreads();
  if (lane == 0)
#pragma unroll
    for (int c = 0; c < 10; ++c) wred[w][c] = psum[c];
  __syncthreads();
  float S[10];
#pragma unroll
  for (int c = 0; c < 10; ++c)
    S[c] = (wred[0][c] + wred[1][c]) + (wred[2][c] + wred[3][c]);
  int r0 = blockIdx.x * 32;
  for (int e = t; e < 320; e += 256) {
    int rl = e / 10, c = e - rl * 10;
    cij_l[e] = expf(bij[(r0 + rl) * 10 + c] - M[c]) / S[c];
  }
  int k0 = blockIdx.x * 256;
  int b0 = blockIdx.y * 32;
  int bg = t >> 4, cog = t & 15;
  int co_base = cog * 10;
  int kk = t >> 4, rr = kk >> 3, ii = kk & 7;
  float acc[2][10];
#pragma unroll
  for (int q = 0; q < 2; ++q)
#pragma unroll
    for (int j = 0; j < 10; ++j) acc[q][j] = 0.f;

  for (int ks2 = 0; ks2 < 16; ++ks2) {
    __syncthreads();
    if (t < 128) {
      int bb = t >> 2, c4 = (t & 3) * 4;
      float4 uv = *(const float4*)&u[(size_t)(b0 + bb) * 9216 + k0 + ks2 * 16 + c4];
      u_t[bb * 17 + c4 + 0] = uv.x;
      u_t[bb * 17 + c4 + 1] = uv.y;
      u_t[bb * 17 + c4 + 2] = uv.z;
      u_t[bb * 17 + c4 + 3] = uv.w;
    }
    {
      int r = r0 + ks2 * 2 + rr;
      const float* Wrow = W + (size_t)(r * 10) * 128;
#pragma unroll
      for (int j = 0; j < 10; ++j) {
        int co = co_base + j;
        int c = co >> 4, o = co & 15;
        w_t[kk * 160 + co] =
            cij_l[(ks2 * 2 + rr) * 10 + c] * Wrow[c * 128 + o * 8 + ii];
      }
    }
    __syncthreads();
#pragma unroll 4
    for (int k2 = 0; k2 < 16; ++k2) {
      float uq[2];
#pragma unroll
      for (int q = 0; q < 2; ++q) uq[q] = u_t[(bg * 2 + q) * 17 + k2];
#pragma unroll
      for (int j = 0; j < 10; ++j) {
        float wv = w_t[k2 * 160 + co_base + j];
#pragma unroll
        for (int q = 0; q < 2; ++q) acc[q][j] = fmaf(uq[q], wv, acc[q][j]);
      }
    }
  }
#pragma unroll
  for (int q = 0; q < 2; ++q)
#pragma unroll
    for (int j = 0; j < 10; ++j)
      atomicAdd(&s[(b0 + bg * 2 + q) * 160 + co_base + j], acc[q][j]);
}

// ---------- final v: reads s2, writes varr + out_v
__global__ __launch_bounds__(256)
void k_v(const float* __restrict__ s, float* __restrict__ v,
         float* __restrict__ outv) {
  int e = blockIdx.x * 256 + threadIdx.x;  // 40960
  float xx = s[e];
  float sn = xx * xx;
  float val = sn * xx / ((1.f + sn) * sqrtf(sn));
  v[e] = val;
  outv[e] = val;
}

// ---------- fused agreement: reads s, applies elementwise squash inline
__global__ __launch_bounds__(256)
void k_Mb(const float* __restrict__ u, const float* __restrict__ s,
          const float* __restrict__ W, float* __restrict__ bij) {
  __shared__ float4 u_c4[16 * 16];
  __shared__ float v_c[16 * 160];
  __shared__ float Ms[64 * 160];
  float* u_c = (float*)u_c4;
  int t = threadIdx.x;
  int ri0 = blockIdx.x * 64;
  int rig = t >> 4, cog = t & 15;
  float acc[4][10];
#pragma unroll
  for (int q = 0; q < 4; ++q)
#pragma unroll
    for (int j = 0; j < 10; ++j) acc[q][j] = 0.f;
  for (int bc = 0; bc < 16; ++bc) {
    __syncthreads();
    {
      int bb = t >> 4, c4 = t & 15;
      u_c4[bb * 16 + c4] =
          *(const float4*)&u[(size_t)(bc * 16 + bb) * 9216 + ri0 + c4 * 4];
    }
    const float* vsl = s + bc * 16 * 160;
#pragma unroll
    for (int j = 0; j < 10; ++j) {
      float xx = vsl[t + 256 * j];
      float sn = xx * xx;
      v_c[t + 256 * j] = sn * xx / ((1.f + sn) * sqrtf(sn));
    }
    __syncthreads();
#pragma unroll 4
    for (int bb = 0; bb < 16; ++bb) {
      float uq[4];
#pragma unroll
      for (int q = 0; q < 4; ++q) uq[q] = u_c[bb * 64 + rig * 4 + q];
#pragma unroll
      for (int j = 0; j < 10; ++j) {
        float vv = v_c[bb * 160 + cog * 10 + j];
#pragma unroll
        for (int q = 0; q < 4; ++q) acc[q][j] = fmaf(uq[q], vv, acc[q][j]);
      }
    }
  }
  __syncthreads();
#pragma unroll
  for (int q = 0; q < 4; ++q)
#pragma unroll
    for (int j = 0; j < 10; ++j)
      Ms[(rig * 4 + q) * 160 + cog * 10 + j] = acc[q][j];
  __syncthreads();
  if (t < 80) {
    int rl = t / 10, c = t - rl * 10;
    int r = blockIdx.x * 8 + rl;
    const float* Wb = W + ((size_t)(r * 10 + c)) * 128;
    float dot = 0.f;
#pragma unroll
    for (int i = 0; i < 8; ++i)
#pragma unroll
      for (int o = 0; o < 16; ++o)
        dot = fmaf(Wb[o * 8 + i], Ms[(rl * 8 + i) * 160 + c * 16 + o], dot);
    bij[r * 10 + c] += dot * (1.f / 256.f);
  }
}

// ---------- class norms, softmax over batch, argmax, mask. grid 1
__global__ __launch_bounds__(256)
void k_cls(const float* __restrict__ v, float* __restrict__ outm,
           int* __restrict__ idxA) {
  __shared__ float red[256];
  __shared__ float Ms[10], Ss[10];
  int t = threadIdx.x;  // = b
  float nrm[10];
#pragma unroll
  for (int c = 0; c < 10; ++c) {
    float sn = 0.f;
#pragma unroll
    for (int o = 0; o < 16; ++o) {
      float xx = v[t * 160 + c * 16 + o];
      sn = fmaf(xx, xx, sn);
    }
    nrm[c] = sqrtf(sn);
  }
  for (int c = 0; c < 10; ++c) {
    red[t] = nrm[c];
    __syncthreads();
    for (int s = 128; s > 0; s >>= 1) {
      if (t < s) red[t] = fmaxf(red[t], red[t + s]);
      __syncthreads();
    }
    if (t == 0) Ms[c] = red[0];
    __syncthreads();
    red[t] = expf(nrm[c] - Ms[c]);
    __syncthreads();
    for (int s = 128; s > 0; s >>= 1) {
      if (t < s) red[t] += red[t + s];
      __syncthreads();
    }
    if (t == 0) Ss[c] = red[0];
    __syncthreads();
  }
  int best = 0;
  float bv = expf(nrm[0] - Ms[0]) / Ss[0];
#pragma unroll
  for (int c = 1; c < 10; ++c) {
    float p = expf(nrm[c] - Ms[c]) / Ss[c];
    if (p > bv) { bv = p; best = c; }
  }
  idxA[t] = best;
#pragma unroll
  for (int c = 0; c < 10; ++c) outm[t * 10 + c] = (c == best) ? 1.f : 0.f;
}

// ---------- fused fc1+fc2. grid (4 n-tiles, 32 b-groups of 8)
__global__ __launch_bounds__(256)
void k_fc12(const float* __restrict__ v, const int* __restrict__ idxA,
            const float* __restrict__ w1, const float* __restrict__ b1,
            const float* __restrict__ w2, const float* __restrict__ b2,
            float* __restrict__ h2) {
  __shared__ float hl[8 * 512];
  int t = threadIdx.x;
  int b0 = blockIdx.y * 8;
  for (int e = t; e < 4096; e += 256) {
    int bb = e >> 9, n = e & 511;
    int b = b0 + bb;
    int ii = idxA[b];
    float a = b1[n];
#pragma unroll
    for (int o = 0; o < 16; ++o)
      a = fmaf(v[b * 160 + ii * 16 + o], w1[(size_t)(ii * 16 + o) * 512 + n], a);
    hl[bb * 512 + n] = fmaxf(a, 0.f);
  }
  __syncthreads();
  int n = blockIdx.x * 256 + t;
  float bias = b2[n];
  float acc[8];
#pragma unroll
  for (int bb = 0; bb < 8; ++bb) acc[bb] = bias;
  for (int k = 0; k < 512; ++k) {
    float w = w2[(size_t)k * 1024 + n];
#pragma unroll
    for (int bb = 0; bb < 8; ++bb) acc[bb] = fmaf(hl[bb * 512 + k], w, acc[bb]);
  }
#pragma unroll
  for (int bb = 0; bb < 8; ++bb)
    h2[(size_t)(b0 + bb) * 1024 + n] = fmaxf(acc[bb], 0.f);
}

// ---------- fc3 + sigmoid -> rec. grid (4 n-tiles, 32 b-groups of 8)
__global__ __launch_bounds__(256)
void k_fc3(const float* __restrict__ h2, const float* __restrict__ w3,
           const float* __restrict__ b3, float* __restrict__ rec) {
  __shared__ float hl[8 * 1024];
  int t = threadIdx.x;
  int n = blockIdx.x * 256 + t;
  int b0 = blockIdx.y * 8;
  const float* src = h2 + (size_t)b0 * 1024;
#pragma unroll
  for (int j = 0; j < 32; ++j) hl[t + 256 * j] = src[t + 256 * j];
  __syncthreads();
  if (n < 784) {
    float bias = b3[n];
    float acc[8];
#pragma unroll
    for (int bb = 0; bb < 8; ++bb) acc[bb] = bias;
    for (int k = 0; k < 1024; ++k) {
      float w = w3[(size_t)k * 784 + n];
#pragma unroll
      for (int bb = 0; bb < 8; ++bb) acc[bb] = fmaf(hl[bb * 1024 + k], w, acc[bb]);
    }
#pragma unroll
    for (int bb = 0; bb < 8; ++bb)
      rec[(size_t)(b0 + bb) * 784 + n] = 1.f / (1.f + expf(-acc[bb]));
  }
}

extern "C" void kernel_launch(void* const* d_in, const int* in_sizes, int n_in,
                              void* d_out, int out_size, void* d_ws, size_t ws_size,
                              hipStream_t stream) {
  const float* x   = (const float*)d_in[0];
  const float* c1w = (const float*)d_in[1];
  const float* c1b = (const float*)d_in[2];
  const float* pw  = (const float*)d_in[3];
  const float* Wc  = (const float*)d_in[5];
  const float* dw1 = (const float*)d_in[6];
  const float* db1 = (const float*)d_in[7];
  const float* dw2 = (const float*)d_in[8];
  const float* db2 = (const float*)d_in[9];
  const float* dw3 = (const float*)d_in[10];
  const float* db3 = (const float*)d_in[11];
  float* out = (float*)d_out;
  float* wsf = (float*)d_ws;

  // workspace layout (float units)
  u16* Bwh     = (u16*)(wsf + 0);          // 2,654,208 f
  u16* Bwl     = (u16*)(wsf + 2654208);    // 2,654,208 f
  u16* yh      = (u16*)(wsf + 5308416);    // 13,107,200 f
  u16* yl      = (u16*)(wsf + 18415616);   // 13,107,200 f
  float* praw2 = wsf + 31522816;           // 2,359,296
  float* u     = wsf + 33882112;           // 2,359,296
  float* bij   = wsf + 36241408;           // 11,520  (contiguous with s0,s1,s2)
  float* s0    = wsf + 36252928;           // 40,960
  float* s1    = wsf + 36293888;           // 40,960
  float* s2    = wsf + 36334848;           // 40,960
  float* varr  = wsf + 36375808;           // 40,960
  float* h2    = wsf + 36416768;           // 262,144
  int*   idxA  = (int*)(wsf + 36678912);   // 256

  float* out_v   = out + 200704;
  float* out_rec = out + 241664;
  float* out_m   = out + 442368;

  k_setup<<<5192, 256, 0, stream>>>(x, out, praw2, bij, pw, Bwh, Bwl, c1w, c1b,
                                    yh, yl);
  k_mfma<<<dim3(36, 36), 256, 0, stream>>>(yh, yl, Bwh, Bwl, praw2);
  k_squash2<<<dim3(4, 256), 256, 0, stream>>>(praw2, u);

  k_s<<<dim3(36, 8), 256, 0, stream>>>(u, Wc, bij, s0);
  k_Mb<<<144, 256, 0, stream>>>(u, s0, Wc, bij);
  k_s<<<dim3(36, 8), 256, 0, stream>>>(u, Wc, bij, s1);
  k_Mb<<<144, 256, 0, stream>>>(u, s1, Wc, bij);
  k_s<<<dim3(36, 8), 256, 0, stream>>>(u, Wc, bij, s2);
  k_v<<<160, 256, 0, stream>>>(s2, varr, out_v);

  k_cls<<<1, 256, 0, stream>>>(varr, out_m, idxA);
  k_fc12<<<dim3(4, 32), 256, 0, stream>>>(varr, idxA, dw1, db1, dw2, db2, h2);
  k_fc3<<<dim3(4, 32), 256, 0, stream>>>(h2, dw3, db3, out_rec);
}